// Round 1
// baseline (31.905 us; speedup 1.0000x reference)
//
#include <hip/hip_runtime.h>

#define IN_DIM 2048
#define OUT_DIM 2048
#define LVAL 256

__global__ __launch_bounds__(256) void ulc_kernel(
    const float* __restrict__ input_r, const float* __restrict__ input_i,
    const float* __restrict__ src_r,   const float* __restrict__ src_i,
    const float* __restrict__ rng,
    const int* __restrict__ i1_frwr, const int* __restrict__ i0_frwr,
    const int* __restrict__ i1_frwi, const int* __restrict__ i0_frwi,
    const int* __restrict__ i1_fiwr, const int* __restrict__ i0_fiwr,
    const int* __restrict__ i1_fiwi, const int* __restrict__ i0_fiwi,
    float* __restrict__ out)
{
    __shared__ float rng_s[LVAL];
    __shared__ int redA[4], redB[4];
    const int tid = threadIdx.x;
    if (tid < LVAL) rng_s[tid] = rng[tid];
    __syncthreads();

    const int o = blockIdx.x;
    const size_t rowoff = (size_t)o * IN_DIM;

    int accA = 0, accB = 0;

    // 2048 columns, 256 threads * 4 elems -> 2 iterations
    #pragma unroll
    for (int j = 0; j < IN_DIM; j += 256 * 4) {
        const int c = j + tid * 4;
        const float4 sr4 = *(const float4*)(src_r + rowoff + c);
        const float4 si4 = *(const float4*)(src_i + rowoff + c);
        const float4 xr4 = *(const float4*)(input_r + c);
        const float4 xi4 = *(const float4*)(input_i + c);
        const int4 a1 = *(const int4*)(i1_frwr + rowoff + c);
        const int4 a0 = *(const int4*)(i0_frwr + rowoff + c);
        const int4 b1 = *(const int4*)(i1_frwi + rowoff + c);
        const int4 b0 = *(const int4*)(i0_frwi + rowoff + c);
        const int4 c1 = *(const int4*)(i1_fiwr + rowoff + c);
        const int4 c0 = *(const int4*)(i0_fiwr + rowoff + c);
        const int4 d1 = *(const int4*)(i1_fiwi + rowoff + c);
        const int4 d0 = *(const int4*)(i0_fiwi + rowoff + c);

        #define ELEM(e)                                                          \
        {                                                                        \
            const float sr = sr4.e, si = si4.e;                                  \
            const bool xr = xr4.e > 0.5f;                                        \
            const bool xi = xi4.e > 0.5f;                                        \
            const int frwr = xr  ? (sr > rng_s[a1.e & 255]) : !(sr > rng_s[a0.e & 255]); \
            const int frwi = xr  ? (si > rng_s[b1.e & 255]) : !(si > rng_s[b0.e & 255]); \
            const int fiwr = xi  ? (sr > rng_s[c1.e & 255]) : !(sr > rng_s[c0.e & 255]); \
            const int fiwi = !xi ? (si > rng_s[d1.e & 255]) : !(si > rng_s[d0.e & 255]); \
            accA += frwr + fiwi;                                                 \
            accB += frwi + fiwr;                                                 \
        }
        ELEM(x) ELEM(y) ELEM(z) ELEM(w)
        #undef ELEM
    }

    // wave (64-lane) reduction
    #pragma unroll
    for (int off = 32; off > 0; off >>= 1) {
        accA += __shfl_down(accA, off);
        accB += __shfl_down(accB, off);
    }
    const int wid = tid >> 6;
    if ((tid & 63) == 0) { redA[wid] = accA; redB[wid] = accB; }
    __syncthreads();
    if (tid == 0) {
        const int sA = redA[0] + redA[1] + redA[2] + redA[3];
        const int sB = redB[0] + redB[1] + redB[2] + redB[3];
        out[o]           = (sA >= 2048) ? 1.0f : 0.0f;  // acc - 2047.5 > 0
        out[OUT_DIM + o] = (sB >= 2048) ? 1.0f : 0.0f;
    }
}

extern "C" void kernel_launch(void* const* d_in, const int* in_sizes, int n_in,
                              void* d_out, int out_size, void* d_ws, size_t ws_size,
                              hipStream_t stream) {
    const float* input_r = (const float*)d_in[0];
    const float* input_i = (const float*)d_in[1];
    const float* src_r   = (const float*)d_in[2];
    const float* src_i   = (const float*)d_in[3];
    const float* rng     = (const float*)d_in[4];
    const int* i1_frwr = (const int*)d_in[5];
    const int* i0_frwr = (const int*)d_in[6];
    const int* i1_frwi = (const int*)d_in[7];
    const int* i0_frwi = (const int*)d_in[8];
    const int* i1_fiwr = (const int*)d_in[9];
    const int* i0_fiwr = (const int*)d_in[10];
    const int* i1_fiwi = (const int*)d_in[11];
    const int* i0_fiwi = (const int*)d_in[12];
    float* out = (float*)d_out;

    ulc_kernel<<<dim3(OUT_DIM), dim3(256), 0, stream>>>(
        input_r, input_i, src_r, src_i, rng,
        i1_frwr, i0_frwr, i1_frwi, i0_frwi,
        i1_fiwr, i0_fiwr, i1_fiwi, i0_fiwi,
        out);
}